// Round 1
// baseline (1775.451 us; speedup 1.0000x reference)
//
#include <hip/hip_runtime.h>
#include <hip/hip_bf16.h>
#include <cstdint>
#include <cstddef>

#define B_ 64
#define T_ 2048
#define D_ 256
#define H_ 256

// ---------------------------------------------------------------------------
// Kernel 1: projection GEMM  xp[b,t,:] = x[b,t,:] @ Wxh + b
// Written IN PLACE into d_out; the recurrence kernel then overwrites each row
// with h_t after consuming it. M = B*T = 131072, N = K = 256. fp32 vector.
// 128x128 tile, 8x8 micro-tile, BK=32.
// ---------------------------------------------------------------------------
#define PM 128
#define PN 128
#define PK 32

__global__ __launch_bounds__(256) void proj_kernel(const float* __restrict__ x,
                                                   const float* __restrict__ Wxh,
                                                   const float* __restrict__ bias,
                                                   float* __restrict__ xp) {
    __shared__ float As[PK][PM + 4];  // [k][m], row stride 132 floats (16B-aligned)
    __shared__ float Bs[PK][PN + 4];  // [k][n]
    const int tid = threadIdx.x;
    const int M0 = blockIdx.x * PM;
    const int N0 = blockIdx.y * PN;
    const int tr = tid >> 4;   // 0..15 -> 8 rows each
    const int tc = tid & 15;   // 0..15 -> 8 cols each

    float acc[8][8];
#pragma unroll
    for (int i = 0; i < 8; ++i)
#pragma unroll
        for (int j = 0; j < 8; ++j) acc[i][j] = 0.f;

    const int fA = tid & 7;   // which float4 along k (A tile)
    const int rA = tid >> 3;  // row 0..31
    const int kB = tid >> 3;  // B row 0..31
    const int fB = tid & 7;   // B f4-col 0..7

    for (int kt = 0; kt < D_; kt += PK) {
        // A tile: x[M0+r][kt..kt+31], transposed into As[k][m]
#pragma unroll
        for (int i = 0; i < 4; ++i) {
            const int r = rA + i * 32;
            const float4 v = *(const float4*)&x[(size_t)(M0 + r) * D_ + kt + fA * 4];
            As[fA * 4 + 0][r] = v.x;
            As[fA * 4 + 1][r] = v.y;
            As[fA * 4 + 2][r] = v.z;
            As[fA * 4 + 3][r] = v.w;
        }
        // B tile: Wxh[kt+k][N0..N0+127]
#pragma unroll
        for (int i = 0; i < 4; ++i) {
            const int c4 = fB + i * 8;  // f4 col 0..31
            const float4 v = *(const float4*)&Wxh[(size_t)(kt + kB) * H_ + N0 + c4 * 4];
            *(float4*)&Bs[kB][c4 * 4] = v;
        }
        __syncthreads();
#pragma unroll
        for (int k = 0; k < PK; ++k) {
            float a[8], bv[8];
            *(float4*)&a[0] = *(const float4*)&As[k][tr * 8];
            *(float4*)&a[4] = *(const float4*)&As[k][tr * 8 + 4];
            *(float4*)&bv[0] = *(const float4*)&Bs[k][tc * 8];
            *(float4*)&bv[4] = *(const float4*)&Bs[k][tc * 8 + 4];
#pragma unroll
            for (int i = 0; i < 8; ++i)
#pragma unroll
                for (int j = 0; j < 8; ++j)
                    acc[i][j] = fmaf(a[i], bv[j], acc[i][j]);
        }
        __syncthreads();
    }

    float bb[8];
    *(float4*)&bb[0] = *(const float4*)&bias[N0 + tc * 8];
    *(float4*)&bb[4] = *(const float4*)&bias[N0 + tc * 8 + 4];
#pragma unroll
    for (int i = 0; i < 8; ++i) {
        const size_t row = (size_t)(M0 + tr * 8 + i);
        float o[8];
#pragma unroll
        for (int j = 0; j < 8; ++j) o[j] = acc[i][j] + bb[j];
        *(float4*)&xp[row * H_ + N0 + tc * 8] = *(float4*)&o[0];
        *(float4*)&xp[row * H_ + N0 + tc * 8 + 4] = *(float4*)&o[4];
    }
}

// ---------------------------------------------------------------------------
// Kernel 2: the recurrence. One block per batch element (64 blocks, 512 thr).
// Whh lives in registers: thread (colg, p) owns cols j0..j0+7 x k k0..k0+15
// (128 VGPRs). h lives in LDS. 16 partial sums per column reduced via LDS.
// io = d_out holding xp; row t is consumed then overwritten with h_t.
// ---------------------------------------------------------------------------
__global__ __launch_bounds__(512) void rnn_kernel(const float* __restrict__ Whh,
                                                  float* __restrict__ io) {
    __shared__ float h_lds[H_];
    __shared__ float part[16][H_ + 4];  // stride 260 floats, 16B-aligned rows

    const int tid = threadIdx.x;
    const int b = blockIdx.x;
    const int colg = tid & 31;  // 32 column groups of 8
    const int p = tid >> 5;     // 0..15 k-chunks of 16
    const int j0 = colg * 8;
    const int k0 = p * 16;

    // Load this thread's 16x8 weight patch (coalesced f4 row reads).
    float w[16][8];
#pragma unroll
    for (int kk = 0; kk < 16; ++kk) {
        const float4 v0 = *(const float4*)&Whh[(size_t)(k0 + kk) * H_ + j0];
        const float4 v1 = *(const float4*)&Whh[(size_t)(k0 + kk) * H_ + j0 + 4];
        w[kk][0] = v0.x; w[kk][1] = v0.y; w[kk][2] = v0.z; w[kk][3] = v0.w;
        w[kk][4] = v1.x; w[kk][5] = v1.y; w[kk][6] = v1.z; w[kk][7] = v1.w;
    }

    float* row_base = io + (size_t)b * T_ * H_;
    float xp0 = 0.f, xp1 = 0.f;
    if (tid < H_) {
        h_lds[tid] = 0.f;
        xp0 = row_base[tid];        // row 0
        xp1 = row_base[H_ + tid];   // row 1
    }
    __syncthreads();

    for (int t = 0; t < T_; ++t) {
        // depth-2 prefetch of xp row t+2 (L3-resident; hidden under compute)
        float xp2 = 0.f;
        if (tid < H_ && (t + 2) < T_) xp2 = row_base[(size_t)(t + 2) * H_ + tid];

        // partials: acc[c] = sum_{kk} h[k0+kk] * Whh[k0+kk][j0+c]
        float acc[8];
#pragma unroll
        for (int c = 0; c < 8; ++c) acc[c] = 0.f;
        const float4* h4 = (const float4*)h_lds;
#pragma unroll
        for (int i = 0; i < 4; ++i) {
            const float4 hv = h4[p * 4 + i];
            const float hs[4] = {hv.x, hv.y, hv.z, hv.w};
#pragma unroll
            for (int q = 0; q < 4; ++q) {
                const int kk = i * 4 + q;
#pragma unroll
                for (int c = 0; c < 8; ++c)
                    acc[c] = fmaf(hs[q], w[kk][c], acc[c]);
            }
        }
        *(float4*)&part[p][j0]     = make_float4(acc[0], acc[1], acc[2], acc[3]);
        *(float4*)&part[p][j0 + 4] = make_float4(acc[4], acc[5], acc[6], acc[7]);
        __syncthreads();

        if (tid < H_) {
            float s = xp0;
#pragma unroll
            for (int pp = 0; pp < 16; ++pp) s += part[pp][tid];
            const float h = tanhf(s);
            h_lds[tid] = h;
            row_base[(size_t)t * H_ + tid] = h;  // overwrite xp row t with h_t
            xp0 = xp1;
            xp1 = xp2;
        }
        __syncthreads();
    }
}

// ---------------------------------------------------------------------------
extern "C" void kernel_launch(void* const* d_in, const int* in_sizes, int n_in,
                              void* d_out, int out_size, void* d_ws, size_t ws_size,
                              hipStream_t stream) {
    const float* x    = (const float*)d_in[0];
    const float* Wxh  = (const float*)d_in[1];
    const float* Whh  = (const float*)d_in[2];
    const float* bias = (const float*)d_in[3];
    float* out = (float*)d_out;

    dim3 pgrid((B_ * T_) / PM, H_ / PN);  // 1024 x 2
    proj_kernel<<<pgrid, dim3(256), 0, stream>>>(x, Wxh, bias, out);
    rnn_kernel<<<dim3(B_), dim3(512), 0, stream>>>(Whh, out);
}